// Round 8
// baseline (1792.590 us; speedup 1.0000x reference)
//
#include <hip/hip_runtime.h>
#include <hip/hip_cooperative_groups.h>

namespace cg = cooperative_groups;

#define NTIPS 512
#define DIM   510          // internal nodes = ntips - 2
#define TOTAL 1022
#define BS    64
#define ITERS 50
#define NTHR  256
#define NROWS (BS * DIM)   // 32640

typedef unsigned short u16;
typedef unsigned int   u32;

// bf16 helpers (RNE, matching XLA/ml_dtypes casts) — identical to R6/R7
__device__ __forceinline__ u16 f2bf(float x) {
    u32 u = __float_as_uint(x);
    return (u16)((u + 0x7FFFu + ((u >> 16) & 1u)) >> 16);
}
__device__ __forceinline__ float bf2f(u16 h) {
    return __uint_as_float(((u32)h) << 16);
}

// ---------------------------------------------------------------------------
// One persistent cooperative kernel, ONE grid sync per fixpoint step.
// Round r: all waves compute X_r (speculative for r = s0+1 — harmless, it
// overwrites X_{r-2}'s buffer only) writing per-row deltas to part slot r&1;
// blocks 0..63 concurrently reduce part slot (r-1)&1 -> go[r-1]; sync; stop
// when go[r-1]==0 (final X = X_{r-1}). Step-1 inputs are the constant
// bf16(1/512) -> no X0 buffer/init needed. Arithmetic order bit-identical to
// the validated R7 kernel (same trajectory, same stop step).
// A (bf16 X_even) in ws; B (bf16 X_odd) in upper half of d_out.
// ---------------------------------------------------------------------------
__global__ __launch_bounds__(NTHR, 8) void persist_kernel(
        const int* __restrict__ edge, u16* __restrict__ A, u16* B,
        float* __restrict__ part, int* __restrict__ go, float* out) {
    cg::grid_group gg = cg::this_grid();
    const int tid   = threadIdx.x;
    const int gidx  = blockIdx.x * NTHR + tid;
    const int wv    = gidx >> 6;                 // global wave id
    const int lane  = tid & 63;
    const int nwave = (gridDim.x * NTHR) >> 6;
    const int nthr_total = gridDim.x * NTHR;

    __shared__ float r2[NTHR];

    if (blockIdx.x == 0 && tid <= ITERS) go[tid] = 0;
    gg.sync();

    const float c0 = bf2f(0x3B00);               // bf16(1/512)
    const float tol_bf = bf2f(f2bf(1e-5f));
    const int f0 = lane << 3;                    // lane owns features f0..f0+7

    int s0 = ITERS;                              // last official step
    for (int s = 1; s <= ITERS; ++s) {
        const u16* src = (s & 1) ? A : B;        // X_{s-1} (s==1: constant)
        u16*       dst = (s & 1) ? B : A;
        float*     pwr = part + (size_t)(s & 1) * NROWS;

        // ---- concurrent reduce of previous step (blocks 0..63) ----
        if (s >= 2 && blockIdx.x < BS) {
            const float* p = part + (size_t)((s - 1) & 1) * NROWS
                                  + (size_t)blockIdx.x * DIM;
            float v = p[tid];
            if (tid + 256 < DIM) v += p[tid + 256];
            r2[tid] = v;
            __syncthreads();
            #pragma unroll
            for (int w = 128; w > 0; w >>= 1) {
                if (tid < w) r2[tid] += r2[tid + w];
                __syncthreads();
            }
            if (tid == 0) {
                const float lnorm = bf2f(f2bf(r2[0] / 261120.0f));
                if (lnorm > tol_bf) atomicOr(&go[s - 1], 1);
            }
        }

        // ---- phase 1: one wave per row ----
        const bool first = (s == 1);
        for (int t = wv; t < NROWS; t += nwave) {
            const int b = t / DIM;               // wave-uniform
            const int i = t - b * DIM;
            const int* e = edge + ((size_t)b * TOTAL + NTIPS + i) * 3;
            const int e0 = e[0], e1 = e[1], e2 = e[2];
            const u16* srcb = src + (size_t)b * DIM * NTIPS;

            float acc[8] = {0.f,0.f,0.f,0.f,0.f,0.f,0.f,0.f};
            #pragma unroll
            for (int k = 0; k < 3; ++k) {
                const int ek = (k == 0) ? e0 : (k == 1) ? e1 : e2;
                if (ek < NTIPS) {                // wave-uniform branch
                    #pragma unroll
                    for (int j = 0; j < 8; ++j)
                        acc[j] += (ek == f0 + j) ? 1.0f : 0.0f;
                } else if (first) {              // X0 row = constant 1/512
                    #pragma unroll
                    for (int j = 0; j < 8; ++j) acc[j] += c0;
                } else {
                    const u16* row = srcb + (size_t)(ek - NTIPS) * NTIPS + f0;
                    const ushort4 a = *reinterpret_cast<const ushort4*>(row);
                    const ushort4 c = *reinterpret_cast<const ushort4*>(row + 4);
                    acc[0] += bf2f(a.x); acc[1] += bf2f(a.y);
                    acc[2] += bf2f(a.z); acc[3] += bf2f(a.w);
                    acc[4] += bf2f(c.x); acc[5] += bf2f(c.y);
                    acc[6] += bf2f(c.z); acc[7] += bf2f(c.w);
                }
            }

            u16 nb[8]; float nf_[8];
            #pragma unroll
            for (int j = 0; j < 8; ++j) {        // mean in f32, RNE cast
                nb[j] = f2bf(acc[j] / 3.0f);
                nf_[j] = bf2f(nb[j]);
            }
            u16* drow = dst + (size_t)t * NTIPS + f0;
            ushort4 s0v; s0v.x = nb[0]; s0v.y = nb[1]; s0v.z = nb[2]; s0v.w = nb[3];
            ushort4 s1v; s1v.x = nb[4]; s1v.y = nb[5]; s1v.z = nb[6]; s1v.w = nb[7];
            *reinterpret_cast<ushort4*>(drow)     = s0v;
            *reinterpret_cast<ushort4*>(drow + 4) = s1v;

            // delta vs old row (bf16-rounded diff), f32 accumulate
            float o[8];
            if (first) {
                #pragma unroll
                for (int j = 0; j < 8; ++j) o[j] = c0;
            } else {
                const u16* orow = srcb + (size_t)i * NTIPS + f0;
                const ushort4 o0 = *reinterpret_cast<const ushort4*>(orow);
                const ushort4 o1 = *reinterpret_cast<const ushort4*>(orow + 4);
                o[0] = bf2f(o0.x); o[1] = bf2f(o0.y);
                o[2] = bf2f(o0.z); o[3] = bf2f(o0.w);
                o[4] = bf2f(o1.x); o[5] = bf2f(o1.y);
                o[6] = bf2f(o1.z); o[7] = bf2f(o1.w);
            }
            float d = 0.f;
            #pragma unroll
            for (int j = 0; j < 8; ++j)
                d += fabsf(bf2f(f2bf(nf_[j] - o[j])));
            #pragma unroll
            for (int off = 32; off > 0; off >>= 1) d += __shfl_down(d, off);
            if (lane == 0) pwr[t] = d;
        }
        gg.sync();

        if (s >= 2) {
            if (__hip_atomic_load(&go[s - 1], __ATOMIC_RELAXED,
                                  __HIP_MEMORY_SCOPE_AGENT) == 0) {
                s0 = s - 1;                      // uniform across the grid
                break;
            }
        }
    }

    if (s0 & 1) {                                // final X in B -> copy to A
        uint4* A4 = reinterpret_cast<uint4*>(A);
        const uint4* B4 = reinterpret_cast<const uint4*>(B);
        const size_t n4 = (size_t)NROWS * NTIPS / 8;
        for (size_t q = gidx; q < n4; q += (size_t)nthr_total) A4[q] = B4[q];
        gg.sync();
    }

    // ---- convert: d_out fp32 = [identity ; f32(bf16 A)] per batch ----
    for (int R = wv; R < BS * TOTAL; R += nwave) {
        const int b = R / TOTAL;                 // wave-uniform
        const int r = R - b * TOTAL;
        float4 lo, hi;
        if (r < NTIPS) {
            lo.x = (r == f0 + 0) ? 1.0f : 0.0f;
            lo.y = (r == f0 + 1) ? 1.0f : 0.0f;
            lo.z = (r == f0 + 2) ? 1.0f : 0.0f;
            lo.w = (r == f0 + 3) ? 1.0f : 0.0f;
            hi.x = (r == f0 + 4) ? 1.0f : 0.0f;
            hi.y = (r == f0 + 5) ? 1.0f : 0.0f;
            hi.z = (r == f0 + 6) ? 1.0f : 0.0f;
            hi.w = (r == f0 + 7) ? 1.0f : 0.0f;
        } else {
            const u16* arow = A + ((size_t)b * DIM + (r - NTIPS)) * NTIPS + f0;
            const ushort4 a = *reinterpret_cast<const ushort4*>(arow);
            const ushort4 c = *reinterpret_cast<const ushort4*>(arow + 4);
            lo.x = bf2f(a.x); lo.y = bf2f(a.y); lo.z = bf2f(a.z); lo.w = bf2f(a.w);
            hi.x = bf2f(c.x); hi.y = bf2f(c.y); hi.z = bf2f(c.z); hi.w = bf2f(c.w);
        }
        float* drow = out + (size_t)R * NTIPS + f0;
        *reinterpret_cast<float4*>(drow)     = lo;
        *reinterpret_cast<float4*>(drow + 4) = hi;
    }
}

extern "C" void kernel_launch(void* const* d_in, const int* in_sizes, int n_in,
                              void* d_out, int out_size, void* d_ws, size_t ws_size,
                              hipStream_t stream) {
    const int* edge = (const int*)d_in[1];       // (BS, TOTAL, 3) int32

    u16*   A    = (u16*)d_ws;                    // bf16 X_even, NROWS*512 u16
    float* part = (float*)(A + (size_t)NROWS * NTIPS);   // 2 slots x NROWS f32
    int*   go   = (int*)(part + 2 * (size_t)NROWS);      // go[0..50]

    u16*   B   = (u16*)d_out + (size_t)BS * TOTAL * NTIPS; // upper half of d_out
    float* out = (float*)d_out;

    // max co-resident blocks (expect 8/CU at <=64 VGPR -> 2048 blocks)
    int occ = 0;
    hipOccupancyMaxActiveBlocksPerMultiprocessor(&occ, (const void*)persist_kernel,
                                                 NTHR, 0);
    if (occ < 1) occ = 1;
    unsigned nblk = (unsigned)occ * 256u;        // 256 CUs on MI355X
    if (nblk > 2048u) nblk = 2048u;
    if (nblk < 64u)   nblk = 64u;                // reducers need 64 blocks

    void* args[] = { (void*)&edge, (void*)&A, (void*)&B,
                     (void*)&part, (void*)&go, (void*)&out };
    hipLaunchCooperativeKernel((const void*)persist_kernel,
                               dim3(nblk), dim3(NTHR), args, 0, stream);
}

// Round 9
// 998.587 us; speedup vs baseline: 1.7951x; 1.7951x over previous
//
#include <hip/hip_runtime.h>

#define NTIPS 512
#define DIM   510                    // internal nodes = ntips - 2
#define TOTAL 1022
#define BS    64
#define ITERS 50
#define SLABF 16                     // features per workgroup slab
#define NSLAB (NTIPS / SLABF)        // 32 slabs per tree
#define NWG   (BS * NSLAB)           // 2048 workgroups
#define NPART ((size_t)ITERS * BS * NSLAB)   // 102400 partial floats

typedef unsigned short u16;
typedef unsigned int   u32;

// bf16 RNE helpers — identical to the validated R6/R7 arithmetic
__device__ __forceinline__ u16 f2bf(float x) {
    u32 u = __float_as_uint(x);
    return (u16)((u + 0x7FFFu + ((u >> 16) & 1u)) >> 16);
}
__device__ __forceinline__ float bf2f(u16 h) {
    return __uint_as_float(((u32)h) << 16);
}
// exact f32 round-to-nearest division by 3 (correctly rounded via double;
// bit-identical to x / 3.0f for all finite f32 x >= 0)
__device__ __forceinline__ float div3(float x) {
    return (float)((double)x * (1.0 / 3.0));
}

// ---------------- zero the partial-delta slab ----------------
__global__ __launch_bounds__(256) void zero_kernel(float* __restrict__ p) {
    size_t g = (size_t)blockIdx.x * 256 + threadIdx.x;
    if (g < NPART) p[g] = 0.f;
}

// ---------------------------------------------------------------------------
// Shared step macro-structure (phase A and C):
// wg = (tree b, slab sl of 16 features). X slab double-buffered bf16 in LDS.
// thread (rg = tid>>2, fq = tid&3): row engine rg handles rows rg, rg+64, ...;
// feature quad fq handles slab-local features 4*fq..4*fq+3 (8B LDS accesses).
// Per step: Jacobi update from src buf -> dst buf, per-thread f32 |delta|
// accumulation (fixed order), 256-way LDS tree reduce -> slab delta dtot.
// dtot == 0  =>  slab is at its bf16 fixpoint forever (deterministic map).
// ---------------------------------------------------------------------------

__global__ __launch_bounds__(256, 4) void phaseA_kernel(
        const int* __restrict__ edge, float* __restrict__ partials) {
    __shared__ u16  Xs[2][DIM * SLABF];     // 32,640 B
    __shared__ u16  eL[DIM * 3];            //  3,060 B
    __shared__ float red[256];

    const int wg  = blockIdx.x;
    const int b   = wg >> 5;                // tree
    const int sl  = wg & 31;                // slab
    const int tid = threadIdx.x;
    const int rg  = tid >> 2;               // row engine 0..63
    const int lbase = (tid & 3) * 4;        // slab-local feature of elem 0
    const int fbase = sl * SLABF + lbase;   // global feature of elem 0

    for (int j = tid; j < DIM * 3; j += 256)
        eL[j] = (u16)edge[((size_t)b * TOTAL + NTIPS) * 3 + j];
    for (int j = tid; j < DIM * SLABF; j += 256) Xs[0][j] = 0x3B00;  // 1/512
    __syncthreads();

    for (int s = 1; s <= ITERS; ++s) {
        const u16* src = Xs[(s - 1) & 1];
        u16*       dst = Xs[s & 1];
        float dacc = 0.f;
        for (int i = rg; i < DIM; i += 64) {
            const int e0 = eL[i * 3 + 0], e1 = eL[i * 3 + 1], e2 = eL[i * 3 + 2];
            float a0 = 0.f, a1 = 0.f, a2 = 0.f, a3 = 0.f;
            #pragma unroll
            for (int k = 0; k < 3; ++k) {
                const int ek = (k == 0) ? e0 : (k == 1) ? e1 : e2;
                const bool inter = (ek >= NTIPS);
                const int  ro    = inter ? (ek - NTIPS) : 0;
                const ushort4 g = *reinterpret_cast<const ushort4*>(
                    src + ro * SLABF + lbase);
                const int dlt = ek - fbase;
                a0 += inter ? bf2f(g.x) : ((dlt == 0) ? 1.f : 0.f);
                a1 += inter ? bf2f(g.y) : ((dlt == 1) ? 1.f : 0.f);
                a2 += inter ? bf2f(g.z) : ((dlt == 2) ? 1.f : 0.f);
                a3 += inter ? bf2f(g.w) : ((dlt == 3) ? 1.f : 0.f);
            }
            const u16 n0 = f2bf(div3(a0)), n1 = f2bf(div3(a1)),
                      n2 = f2bf(div3(a2)), n3 = f2bf(div3(a3));
            const ushort4 ov = *reinterpret_cast<const ushort4*>(
                src + i * SLABF + lbase);
            ushort4 nv; nv.x = n0; nv.y = n1; nv.z = n2; nv.w = n3;
            *reinterpret_cast<ushort4*>(dst + i * SLABF + lbase) = nv;
            dacc += fabsf(bf2f(f2bf(bf2f(n0) - bf2f(ov.x))));
            dacc += fabsf(bf2f(f2bf(bf2f(n1) - bf2f(ov.y))));
            dacc += fabsf(bf2f(f2bf(bf2f(n2) - bf2f(ov.z))));
            dacc += fabsf(bf2f(f2bf(bf2f(n3) - bf2f(ov.w))));
        }
        red[tid] = dacc;
        __syncthreads();
        #pragma unroll
        for (int w = 128; w > 0; w >>= 1) {
            if (tid < w) red[tid] += red[tid + w];
            __syncthreads();
        }
        const float dtot = red[0];
        if (tid == 0)
            partials[((size_t)(s - 1) * BS + b) * NSLAB + sl] = dtot;
        __syncthreads();                    // red reuse + dst visibility
        if (dtot == 0.f) break;             // frozen: later deltas exactly 0
    }
}

// ---------------------------------------------------------------------------
// findS: one wave. Replicates the while_loop stop rule from the partials:
// S = first s with all trees' bf16(lnorm_s) <= bf16(1e-5), capped at ITERS.
// ---------------------------------------------------------------------------
__global__ void findS_kernel(const float* __restrict__ partials,
                             int* __restrict__ ctrl) {
    const int lane = threadIdx.x;           // 64 lanes = trees
    const float tol_bf = bf2f(f2bf(1e-5f));
    int S = ITERS;
    for (int s = 1; s <= ITERS; ++s) {
        const float* p = partials + ((size_t)(s - 1) * BS + lane) * NSLAB;
        float t = 0.f;
        #pragma unroll
        for (int k = 0; k < NSLAB; ++k) t += p[k];
        const float lnorm = bf2f(f2bf(t / 261120.0f));   // /(DIM*NTIPS)
        if (__ballot(lnorm > tol_bf) == 0ULL) { S = s; break; }
    }
    if (lane == 0) ctrl[0] = S;
}

// ---------------------------------------------------------------------------
// phaseC: identical trajectory, exactly S steps (freeze early-exit is a
// bit-exact shortcut), then write the fp32 output column slab.
// ---------------------------------------------------------------------------
__global__ __launch_bounds__(256, 4) void phaseC_kernel(
        const int* __restrict__ edge, const int* __restrict__ ctrl,
        float* __restrict__ out) {
    __shared__ u16  Xs[2][DIM * SLABF];
    __shared__ u16  eL[DIM * 3];
    __shared__ float red[256];

    const int wg  = blockIdx.x;
    const int b   = wg >> 5;
    const int sl  = wg & 31;
    const int tid = threadIdx.x;
    const int rg  = tid >> 2;
    const int lbase = (tid & 3) * 4;
    const int fbase = sl * SLABF + lbase;

    for (int j = tid; j < DIM * 3; j += 256)
        eL[j] = (u16)edge[((size_t)b * TOTAL + NTIPS) * 3 + j];
    for (int j = tid; j < DIM * SLABF; j += 256) Xs[0][j] = 0x3B00;
    const int S = ctrl[0];                  // uniform
    __syncthreads();

    const u16* cur = Xs[0];
    for (int s = 1; s <= S; ++s) {
        const u16* src = Xs[(s - 1) & 1];
        u16*       dst = Xs[s & 1];
        float dacc = 0.f;
        for (int i = rg; i < DIM; i += 64) {
            const int e0 = eL[i * 3 + 0], e1 = eL[i * 3 + 1], e2 = eL[i * 3 + 2];
            float a0 = 0.f, a1 = 0.f, a2 = 0.f, a3 = 0.f;
            #pragma unroll
            for (int k = 0; k < 3; ++k) {
                const int ek = (k == 0) ? e0 : (k == 1) ? e1 : e2;
                const bool inter = (ek >= NTIPS);
                const int  ro    = inter ? (ek - NTIPS) : 0;
                const ushort4 g = *reinterpret_cast<const ushort4*>(
                    src + ro * SLABF + lbase);
                const int dlt = ek - fbase;
                a0 += inter ? bf2f(g.x) : ((dlt == 0) ? 1.f : 0.f);
                a1 += inter ? bf2f(g.y) : ((dlt == 1) ? 1.f : 0.f);
                a2 += inter ? bf2f(g.z) : ((dlt == 2) ? 1.f : 0.f);
                a3 += inter ? bf2f(g.w) : ((dlt == 3) ? 1.f : 0.f);
            }
            const u16 n0 = f2bf(div3(a0)), n1 = f2bf(div3(a1)),
                      n2 = f2bf(div3(a2)), n3 = f2bf(div3(a3));
            const ushort4 ov = *reinterpret_cast<const ushort4*>(
                src + i * SLABF + lbase);
            ushort4 nv; nv.x = n0; nv.y = n1; nv.z = n2; nv.w = n3;
            *reinterpret_cast<ushort4*>(dst + i * SLABF + lbase) = nv;
            dacc += fabsf(bf2f(f2bf(bf2f(n0) - bf2f(ov.x))));
            dacc += fabsf(bf2f(f2bf(bf2f(n1) - bf2f(ov.y))));
            dacc += fabsf(bf2f(f2bf(bf2f(n2) - bf2f(ov.z))));
            dacc += fabsf(bf2f(f2bf(bf2f(n3) - bf2f(ov.w))));
        }
        red[tid] = dacc;
        __syncthreads();
        #pragma unroll
        for (int w = 128; w > 0; w >>= 1) {
            if (tid < w) red[tid] += red[tid + w];
            __syncthreads();
        }
        const float dtot = red[0];
        __syncthreads();
        cur = dst;
        if (dtot == 0.f) break;             // X frozen == X_S
    }

    // output: fp32 column slab [identity rows ; f32(bf16 X_S)]
    for (int r = rg; r < TOTAL; r += 64) {
        float4 v;
        if (r < NTIPS) {
            v.x = (r == fbase + 0) ? 1.f : 0.f;
            v.y = (r == fbase + 1) ? 1.f : 0.f;
            v.z = (r == fbase + 2) ? 1.f : 0.f;
            v.w = (r == fbase + 3) ? 1.f : 0.f;
        } else {
            const ushort4 g = *reinterpret_cast<const ushort4*>(
                cur + (r - NTIPS) * SLABF + lbase);
            v.x = bf2f(g.x); v.y = bf2f(g.y); v.z = bf2f(g.z); v.w = bf2f(g.w);
        }
        *reinterpret_cast<float4*>(
            out + ((size_t)b * TOTAL + r) * NTIPS + fbase) = v;
    }
}

extern "C" void kernel_launch(void* const* d_in, const int* in_sizes, int n_in,
                              void* d_out, int out_size, void* d_ws, size_t ws_size,
                              hipStream_t stream) {
    const int* edge = (const int*)d_in[1];       // (BS, TOTAL, 3) int32
    float* out = (float*)d_out;                  // (BS, TOTAL, 512) fp32

    float* partials = (float*)d_ws;              // [ITERS][BS][NSLAB] f32
    int*   ctrl     = (int*)((char*)d_ws + NPART * sizeof(float));

    zero_kernel<<<(unsigned)((NPART + 255) / 256), 256, 0, stream>>>(partials);
    phaseA_kernel<<<NWG, 256, 0, stream>>>(edge, partials);
    findS_kernel<<<1, 64, 0, stream>>>(partials, ctrl);
    phaseC_kernel<<<NWG, 256, 0, stream>>>(edge, ctrl, out);
}